// Round 13
// baseline (102.490 us; speedup 1.0000x reference)
//
#include <hip/hip_runtime.h>
#include <hip/hip_bf16.h>
#include <math.h>

#define NSLICE 2048
#define NH 133     // output spatial size (int(128*1+4)+1)
#define NP 144     // padded to 9 tiles of 16
#define NT 576     // 9 waves per block
#define SPB 4      // slices per block -> 512 blocks = exactly 2/CU, 1 generation
#define NBLK (NSLICE / SPB)
#define NSTRIP (SPB * 8)        // 32 strips of 16 rows per block

// LDS map (78,848 B; x2 = 157,696 <= 163,840 -> 2 blocks/CU):
//   [0, 32768)       4 strip bufs x 8192 B (16 rows x 512 B fp32, col-swizzled)
//   [32768, 69632)   M1_fm : 36 frags (it*4+kk) x 1024 B, bf16 fragment-major
//   [69632, 78848)   scratch: 9 waves x 1024 B (per-wave repack)
#define M1B  32768
#define SCR  69632
#define LDSB 78848

typedef __attribute__((ext_vector_type(8))) short bf16x8;   // 8 bf16 = 4 VGPRs
typedef __attribute__((ext_vector_type(4))) float f32x4;

typedef __attribute__((address_space(3))) unsigned int  lds_u32;
typedef const __attribute__((address_space(1))) unsigned int glb_u32;

#define GLOAD_LDS16(gsrc, ldst) \
    __builtin_amdgcn_global_load_lds((glb_u32*)(gsrc), (lds_u32*)(ldst), 16, 0, 0)

#define VMW(n)  asm volatile("s_waitcnt vmcnt(" #n ")" ::: "memory")
// raw barrier fenced on both sides; vmcnt deliberately NOT drained here
#define BAR() do { __builtin_amdgcn_sched_barrier(0); \
                   asm volatile("s_waitcnt lgkmcnt(0)" ::: "memory"); \
                   __builtin_amdgcn_s_barrier(); \
                   __builtin_amdgcn_sched_barrier(0); } while (0)

__device__ __forceinline__ unsigned f2bf(float f) {
    __hip_bfloat16 h = __float2bfloat16(f);   // round-to-nearest-even
    union { __hip_bfloat16 b; unsigned short u; } c; c.b = h; return (unsigned)c.u;
}

// ---------------------------------------------------------------------------
// prep_M: combined (IDCT * mask * DCT) matrices, bf16, in workspace.
//   M[row, p] = sum_{u=0}^{127} D2[u,row] * mask[u] * D1[u,p]
// M1 emitted FRAGMENT-MAJOR (R10-proven); M2 row-major.
// ---------------------------------------------------------------------------
__global__ void prep_M(const float* __restrict__ rw,
                       unsigned short* __restrict__ M1,
                       unsigned short* __restrict__ M2) {
    __shared__ float t1[512];
    __shared__ float t2[532];
    const int b   = blockIdx.x;        // 0..287
    const int m   = b / NP;            // 0 -> M1, 1 -> M2
    const int row = b - m * NP;        // 0..143
    const int p   = threadIdx.x;       // 0..127

    const float c1  = (float)(M_PI / 256.0);
    const float c2  = (float)(M_PI / 266.0);
    const float s1n = 0.125f;                  // sqrt(2/128)
    const float s10 = 0.08838834764831844f;    // s1n/sqrt(2)
    const float s2n = 0.12262786485246718f;    // sqrt(2/133)
    const float s20 = 0.08671099951921386f;    // s2n/sqrt(2)

    for (int k = p; k < 512; k += 128) t1[k] = cosf((float)k * c1) * s1n;
    for (int k = p; k < 532; k += 128) t2[k] = cosf((float)k * c2) * s2n;
    __syncthreads();

    float val = 0.0f;
    if (row < NH) {
        float r = rw[m];
        float minr = fmaxf((1.0f - 4.0f) / 128.0f, 0.0f);
        r = fminf(fmaxf(r, minr), 2.0f);
        const float crop = 128.0f * r;

        const int tp = 2 * p + 1;
        const int ti = 2 * row + 1;
        float acc = s10 * s20;        // u = 0 term (mask(0) == 1 since crop >= 0)
        int a1 = 0, a2 = 0;
        for (int u = 1; u < 128; ++u) {
            a1 = (a1 + tp) & 511;
            a2 += ti; if (a2 >= 532) a2 -= 532;
            float mask = fminf(fmaxf((4.0f + crop - (float)u) * 0.25f, 0.0f), 1.0f);
            acc = fmaf(t1[a1] * mask, t2[a2], acc);
        }
        val = acc;
    }
    const unsigned short v16 = (unsigned short)f2bf(val);
    if (m == 0) {
        const int it = row >> 4, rr = row & 15;
        const int k2 = p >> 5, gg = (p >> 3) & 3, e = p & 7;
        M1[(size_t)((it * 4 + k2) * 512 + (gg * 16 + rr) * 8 + e)] = v16;
    } else {
        M2[(size_t)row * 128 + p] = v16;
    }
}

// ---------------------------------------------------------------------------
// dct_resize: 512 persistent blocks (2/CU), 9 waves, 4 slices each.
// X streams in 16-row fp32 strips (8 KB) through 4 buffers via
// global_load_lds, issue-ahead-3, counted vmcnt (never a full drain in the
// main loop).  Stage A consumes each strip immediately (p-tiles are
// K-independent); the full-K result accumulates per-wave in u2 registers
// (R10 dataflow).  Strip source is col-pre-swizzled (gcol ^= row&7) so
// stage-A reads are bank-conflict-free; strip row index == lane r.
// End of slice: per-wave repack (scratch, barrier-free) + stage B vs
// LDS-resident fragment-major M1 (lane*16 reads, conflict-free) + guarded
// stores. vmcnt counts include the 36 stores/wave that straddle slice
// boundaries: phases 0-2 of slices>=1 wait vmcnt(38), else vmcnt(2).
// ---------------------------------------------------------------------------
__global__ __launch_bounds__(NT, 4) void dct_resize(
        const float* __restrict__ x,
        const unsigned short* __restrict__ M1f,
        const unsigned short* __restrict__ M2,
        float* __restrict__ out) {
    __shared__ __align__(16) unsigned char lds[LDSB];

    const int tid  = threadIdx.x;
    const int w    = tid >> 6;      // wave 0..8
    const int lane = tid & 63;
    const int r    = lane & 15;     // fragment row/col index
    const int g    = lane >> 4;     // k-group 0..3

    const float* xbase = x   + (size_t)blockIdx.x * SPB * (128 * 128);
    float*       obase = out + (size_t)blockIdx.x * SPB * (NH * NH);

    const int j0 = w * 16;          // this wave's output-column tile

    // ---- bm2 register fragments FIRST; drain so the vm queue is clean ----
    bf16x8 bm2[4];
    #pragma unroll
    for (int kk = 0; kk < 4; ++kk)
        bm2[kk] = *(const bf16x8*)(M2 + (size_t)(j0 + r) * 128 + kk * 32 + g * 8);
    VMW(0);
    __builtin_amdgcn_sched_barrier(0);

    // ---- strip loader mapping: thread t<512 stages granule t of a strip.
    // dest linear: buf + tid*16.  source col granule pre-swizzled by row&7.
    const int srow = (tid >> 5) & 15;                 // strip-local row 0..15
    const int sgc  = (tid & 31) ^ (srow & 7);         // swizzled 16B column

    #define ISSUE(n) do { if (tid < 512 && (n) < NSTRIP) {                     \
        const float* _s = xbase + (size_t)((n) >> 3) * (128 * 128)             \
                        + (size_t)((((n) & 7) * 16 + srow) * 128) + sgc * 4;   \
        GLOAD_LDS16(_s, lds + ((n) & 3) * 8192 + tid * 16); } } while (0)

    // ---- prologue: M1_fm copy (4x16B per thread) + strips 0,1,2 ----
    #pragma unroll
    for (int v = 0; v < 4; ++v)
        GLOAD_LDS16(M1f + (size_t)(v * NT + tid) * 8,
                    lds + M1B + (v * NT + tid) * 16);
    ISSUE(0); ISSUE(1); ISSUE(2);

    #pragma unroll
    for (int s = 0; s < SPB; ++s) {
        uint2 u2[8];
        #pragma unroll
        for (int p8 = 0; p8 < 8; ++p8) {
            const int n = s * 8 + p8;
            // wait for strip n; queue may also hold last slice's 36 stores
            if (s == 0 || p8 >= 3) { VMW(2); } else { VMW(38); }
            BAR();
            ISSUE(n + 3);

            // ---- stage A on strip n (p-tile p8): lane (r,g) reads its
            // 8 fp32 via two swizzled b128s, cvt, MFMA vs bm2 ----
            const unsigned char* sb = lds + (n & 3) * 8192 + r * 512;
            f32x4 acc = {0.f, 0.f, 0.f, 0.f};
            #pragma unroll
            for (int kk = 0; kk < 4; ++kk) {
                const int c0 = kk * 8 + g * 2;
                const float4 lo = *(const float4*)(sb + ((c0)     ^ (r & 7)) * 16);
                const float4 hi = *(const float4*)(sb + ((c0 + 1) ^ (r & 7)) * 16);
                union { bf16x8 b; unsigned short us[8]; } fr;
                fr.us[0] = (unsigned short)f2bf(lo.x);
                fr.us[1] = (unsigned short)f2bf(lo.y);
                fr.us[2] = (unsigned short)f2bf(lo.z);
                fr.us[3] = (unsigned short)f2bf(lo.w);
                fr.us[4] = (unsigned short)f2bf(hi.x);
                fr.us[5] = (unsigned short)f2bf(hi.y);
                fr.us[6] = (unsigned short)f2bf(hi.z);
                fr.us[7] = (unsigned short)f2bf(hi.w);
                acc = __builtin_amdgcn_mfma_f32_16x16x32_bf16(fr.b, bm2[kk], acc, 0, 0, 0);
            }
            // lane holds T[j0+r][p8*16 + g*4 + q], q = 0..3 (D layout)
            u2[p8].x = f2bf(acc[0]) | (f2bf(acc[1]) << 16);
            u2[p8].y = f2bf(acc[2]) | (f2bf(acc[3]) << 16);
        }

        // ---- per-wave repack: D layout (4-consec p) -> B-frag (8-consec p)
        // In-wave DS ordering -> barrier-free (R4/R10-proven).
        unsigned char* scr = lds + SCR + w * 1024;
        bf16x8 bfrag[4];
        #pragma unroll
        for (int kk = 0; kk < 4; ++kk) {
            *(uint2*)(scr + (g)     * 128 + r * 8) = u2[2 * kk];
            *(uint2*)(scr + (4 + g) * 128 + r * 8) = u2[2 * kk + 1];
            const uint2 lo2 = *(const uint2*)(scr + (2 * g)     * 128 + r * 8);
            const uint2 hi2 = *(const uint2*)(scr + (2 * g + 1) * 128 + r * 8);
            union { uint4 u; bf16x8 b; } cv;
            cv.u = make_uint4(lo2.x, lo2.y, hi2.x, hi2.y);
            bfrag[kk] = cv.b;
        }

        // ---- Stage B: out[i][j0+r] = sum_p M1[i][p] * T[j0+r][p] ----
        float* os = obase + (size_t)s * (NH * NH);
        const int jc = j0 + r;
        #pragma unroll
        for (int it = 0; it < 9; ++it) {
            f32x4 acc = {0.f, 0.f, 0.f, 0.f};
            #pragma unroll
            for (int kk = 0; kk < 4; ++kk) {
                bf16x8 a = *(const bf16x8*)(lds + M1B + (it * 4 + kk) * 1024 + lane * 16);
                acc = __builtin_amdgcn_mfma_f32_16x16x32_bf16(a, bfrag[kk], acc, 0, 0, 0);
            }
            if (jc < NH) {
                #pragma unroll
                for (int q = 0; q < 4; ++q) {
                    const int i = it * 16 + g * 4 + q;
                    if (i < NH) os[(size_t)i * NH + jc] = acc[q];
                }
            }
        }
        // stores (36/wave) stay in the vm queue; next slice's phase counts
        // account for them (vmcnt(38) at phases 0-2, drained by phase 3).
    }
    #undef ISSUE
}

extern "C" void kernel_launch(void* const* d_in, const int* in_sizes, int n_in,
                              void* d_out, int out_size, void* d_ws, size_t ws_size,
                              hipStream_t stream) {
    const float* x  = (const float*)d_in[0];
    const float* rw = (const float*)d_in[1];
    float* outp = (float*)d_out;
    unsigned short* M1 = (unsigned short*)d_ws;     // 18432 ushorts, fragment-major
    unsigned short* M2 = M1 + 18432;                // 18432 ushorts, row-major

    prep_M<<<dim3(2 * NP), dim3(128), 0, stream>>>(rw, M1, M2);
    dct_resize<<<dim3(NBLK), dim3(NT), 0, stream>>>(x, M1, M2, outp);
}